// Round 4
// baseline (180.624 us; speedup 1.0000x reference)
//
#include <hip/hip_runtime.h>

#define E_EDGES 320000
#define HID 128
#define K3 384
#define NR 16
#define TILE_E 64
#define NTILES (E_EDGES / TILE_E)   // 5000
#define HS 392   // padded K stride (bf16 elems), row = 784 B (16B-aligned)
#define RS 24    // padded NR stride
#define WT_BYTES (HID * K3 * 2)     // 98304

typedef float f32x16 __attribute__((ext_vector_type(16)));
typedef short short8 __attribute__((ext_vector_type(8)));

__device__ __forceinline__ unsigned short f2bf(float x) {
  union { float f; unsigned u; } v; v.f = x;
  unsigned u = v.u + 0x7fffu + ((v.u >> 16) & 1u);   // RNE
  return (unsigned short)(u >> 16);
}
__device__ __forceinline__ unsigned pk2(float a, float b) {
  union { float f; unsigned u; } va, vb; va.f = a; vb.f = b;
  unsigned ua = va.u + 0x7fffu + ((va.u >> 16) & 1u);
  unsigned ub = vb.u + 0x7fffu + ((vb.u >> 16) & 1u);
  return (ua >> 16) | (ub & 0xffff0000u);
}

#define BAR() asm volatile("s_waitcnt lgkmcnt(0)\n\ts_barrier" ::: "memory")

// ---- one-time prep: Wt[col][k] bf16 <- Wlin[k][col] f32 ----
__global__ __launch_bounds__(256)
void wt_prep_kernel(const float* __restrict__ Wlin, unsigned short* __restrict__ Wt) {
  int i = blockIdx.x * 256 + threadIdx.x;   // 0..49151, i = col*384 + k
  if (i < K3 * HID) {
    int col = i / K3, k = i - col * K3;
    Wt[i] = f2bf(Wlin[k * HID + col]);
  }
}

// =============== main kernel: 2 blocks/CU, B streamed from L2 ===============
__global__ __launch_bounds__(512, 4)
void edge_feat_kernel2(const float* __restrict__ node_embs,
                       const int* __restrict__ eidx,
                       const float* __restrict__ ew,
                       const float* __restrict__ Wrbf0,
                       const float* __restrict__ brbf0,
                       const unsigned short* __restrict__ Wt,
                       const float* __restrict__ blin,
                       const float* __restrict__ Wrbf1,
                       float* __restrict__ out)
{
  // LDS: 50176 + 3072 = 53248 B -> 2 blocks/CU
  __shared__ __align__(16) unsigned short hT[TILE_E * HS];
  __shared__ __align__(16) unsigned short rbfb[TILE_E * RS];

  const int t    = threadIdx.x;
  const int lane = t & 63;
  const int w    = t >> 6;
  const int er   = w >> 2;
  const int cc   = w & 3;
  const int l31  = lane & 31;
  const int hi   = lane >> 5;
  const int koff = hi * 8;
  const int arow = er * 32 + l31;
  const int bcol = cc * 32 + l31;
  const float bl = blin[bcol];
  const float b0 = brbf0[bcol];

  short8 w0f, w1f;
  #pragma unroll
  for (int j = 0; j < 8; ++j) {
    w0f[j] = (short)f2bf(Wrbf0[(koff + j) * HID + bcol]);
    w1f[j] = (short)f2bf(Wrbf1[(koff + j) * HID + bcol]);
  }

  for (int tile = blockIdx.x; tile < NTILES; tile += (int)gridDim.x) {
    const int e0 = tile * TILE_E;

    // ---- stage: gathers -> hT[:,0:256), rbf -> rbfb ----
    #pragma unroll
    for (int rep = 0; rep < 8; ++rep) {
      int idx   = rep * 512 + t;
      int which = idx >> 11, r2 = idx & 2047;
      int e_loc = r2 >> 5, q = r2 & 31;
      int node  = eidx[which * E_EDGES + e0 + e_loc];
      const float4 v = ((const float4*)node_embs)[node * 32 + q];
      uint2 pv; pv.x = pk2(v.x, v.y); pv.y = pk2(v.z, v.w);
      *(uint2*)&hT[e_loc * HS + which * 128 + q * 4] = pv;
    }
    #pragma unroll
    for (int rep = 0; rep < 2; ++rep) {
      int i = rep * 512 + t;
      int e_loc = i >> 4, r = i & 15;
      float d = ew[e0 + e_loc];
      float v = 0.63245553f * __sinf(d * (float)(r + 1) * 0.62831853f) / d;
      rbfb[e_loc * RS + r] = f2bf(v);
    }
    BAR();

    // ---- rbf0 = silu(rbf@W0 + b0) -> hT[:,256:384) ----
    {
      f32x16 r0 = {0,0,0,0,0,0,0,0,0,0,0,0,0,0,0,0};
      short8 ra = *(const short8*)&rbfb[arow * RS + koff];
      r0 = __builtin_amdgcn_mfma_f32_32x32x16_bf16(ra, w0f, r0, 0, 0, 0);
      #pragma unroll
      for (int i = 0; i < 16; ++i) {
        int row = (i & 3) + 8 * (i >> 2) + 4 * hi;
        float x = r0[i] + b0;
        float s = x / (1.f + __expf(-x));
        hT[(er * 32 + row) * HS + 256 + bcol] = f2bf(s);
      }
    }
    BAR();

    // ---- main MFMA: B-frags streamed from global (L2), two 12-deep halves ----
    f32x16 acc = {0,0,0,0,0,0,0,0,0,0,0,0,0,0,0,0};
    {
      short8 bf[12];
      #pragma unroll
      for (int j = 0; j < 12; ++j)
        bf[j] = *(const short8*)&Wt[bcol * K3 + j * 16 + koff];
      #pragma unroll
      for (int ks = 0; ks < 12; ++ks) {
        short8 a = *(const short8*)&hT[arow * HS + ks * 16 + koff];
        acc = __builtin_amdgcn_mfma_f32_32x32x16_bf16(a, bf[ks], acc, 0, 0, 0);
      }
      #pragma unroll
      for (int j = 0; j < 12; ++j)
        bf[j] = *(const short8*)&Wt[bcol * K3 + (12 + j) * 16 + koff];
      #pragma unroll
      for (int ks = 0; ks < 12; ++ks) {
        short8 a = *(const short8*)&hT[arow * HS + (12 + ks) * 16 + koff];
        acc = __builtin_amdgcn_mfma_f32_32x32x16_bf16(a, bf[ks], acc, 0, 0, 0);
      }
    }

    // ---- sacc = rbf @ W1 (rbfb still valid) ----
    f32x16 sacc = {0,0,0,0,0,0,0,0,0,0,0,0,0,0,0,0};
    {
      short8 ra = *(const short8*)&rbfb[arow * RS + koff];
      sacc = __builtin_amdgcn_mfma_f32_32x32x16_bf16(ra, w1f, sacc, 0, 0, 0);
    }

    // ---- epilogue ----
    #pragma unroll
    for (int i = 0; i < 16; ++i) {
      int row   = (i & 3) + 8 * (i >> 2) + 4 * hi;
      int e_loc = er * 32 + row;
      float x  = acc[i] + bl;
      float e1 = x / (1.f + __expf(-x));
      float e2 = sacc[i] * e1;
      long gi = (long)(e0 + e_loc) * HID + bcol;
      __builtin_nontemporal_store(e1, &out[gi]);
      __builtin_nontemporal_store(e2, &out[(long)E_EDGES * HID + gi]);
    }
    BAR();  // all LDS reads done before next tile's stage overwrites
  }
}

// =============== fallback (R3 kernel, used only if ws too small) ===============
__global__ __launch_bounds__(512, 2)
void edge_feat_kernel_fb(const float* __restrict__ node_embs,
                         const int* __restrict__ eidx,
                         const float* __restrict__ ew,
                         const float* __restrict__ Wrbf0,
                         const float* __restrict__ brbf0,
                         const float* __restrict__ Wlin,
                         const float* __restrict__ blin,
                         const float* __restrict__ Wrbf1,
                         float* __restrict__ out)
{
  __shared__ __align__(16) unsigned short hT[2][TILE_E * HS];
  __shared__ __align__(16) unsigned short rbfb[2][TILE_E * RS];

  const int t    = threadIdx.x;
  const int lane = t & 63;
  const int w    = t >> 6;
  const int er   = w >> 2;
  const int cc   = w & 3;
  const int l31  = lane & 31;
  const int hi   = lane >> 5;
  const int koff = hi * 8;
  const int arow = er * 32 + l31;
  const int bcol = cc * 32 + l31;
  const float bl = blin[bcol];
  const float b0 = brbf0[bcol];

  {
    unsigned short* WtL = &hT[0][0];
    for (int i = t; i < K3 * HID; i += 512) {
      int k = i >> 7, col = i & 127;
      WtL[col * HS + k] = f2bf(Wlin[i]);
    }
    BAR();
  }
  short8 wb[24];
  #pragma unroll
  for (int ks = 0; ks < 24; ++ks)
    wb[ks] = *(const short8*)&hT[0][bcol * HS + ks * 16 + koff];
  asm volatile("s_waitcnt lgkmcnt(0)" ::: "memory");
  __builtin_amdgcn_s_barrier();

  short8 w0f, w1f;
  #pragma unroll
  for (int j = 0; j < 8; ++j) {
    w0f[j] = (short)f2bf(Wrbf0[(koff + j) * HID + bcol]);
    w1f[j] = (short)f2bf(Wrbf1[(koff + j) * HID + bcol]);
  }

  int tile = blockIdx.x;
  {
    #pragma unroll
    for (int rep = 0; rep < 8; ++rep) {
      int idx   = rep * 512 + t;
      int which = idx >> 11, r2 = idx & 2047;
      int e_loc = r2 >> 5, q = r2 & 31;
      int node  = eidx[which * E_EDGES + tile * TILE_E + e_loc];
      const float4 v = ((const float4*)node_embs)[node * 32 + q];
      uint2 pv; pv.x = pk2(v.x, v.y); pv.y = pk2(v.z, v.w);
      *(uint2*)&hT[0][e_loc * HS + which * 128 + q * 4] = pv;
    }
    #pragma unroll
    for (int rep = 0; rep < 2; ++rep) {
      int i = rep * 512 + t;
      int e_loc = i >> 4, r = i & 15;
      float d = ew[tile * TILE_E + e_loc];
      float v = 0.63245553f * __sinf(d * (float)(r + 1) * 0.62831853f) / d;
      rbfb[0][e_loc * RS + r] = f2bf(v);
    }
  }
  BAR();

  int cur = 0;
  for (; tile < NTILES; tile += (int)gridDim.x) {
    const int nt = tile + (int)gridDim.x;
    const bool hasnext = (nt < NTILES);
    const int e0 = tile * TILE_E;

    float4 g4[8];
    float dv[2];
    if (hasnext) {
      #pragma unroll
      for (int rep = 0; rep < 8; ++rep) {
        int idx   = rep * 512 + t;
        int which = idx >> 11, r2 = idx & 2047;
        int e_loc = r2 >> 5, q = r2 & 31;
        int node  = eidx[which * E_EDGES + nt * TILE_E + e_loc];
        g4[rep] = ((const float4*)node_embs)[node * 32 + q];
      }
      #pragma unroll
      for (int rep = 0; rep < 2; ++rep)
        dv[rep] = ew[nt * TILE_E + ((rep * 512 + t) >> 4)];
    }

    f32x16 r0   = {0,0,0,0,0,0,0,0,0,0,0,0,0,0,0,0};
    f32x16 sacc = {0,0,0,0,0,0,0,0,0,0,0,0,0,0,0,0};
    short8 ra = *(const short8*)&rbfb[cur][arow * RS + koff];
    r0   = __builtin_amdgcn_mfma_f32_32x32x16_bf16(ra, w0f, r0, 0, 0, 0);
    sacc = __builtin_amdgcn_mfma_f32_32x32x16_bf16(ra, w1f, sacc, 0, 0, 0);
    #pragma unroll
    for (int i = 0; i < 16; ++i) {
      int row = (i & 3) + 8 * (i >> 2) + 4 * hi;
      float x = r0[i] + b0;
      float s = x / (1.f + __expf(-x));
      hT[cur][(er * 32 + row) * HS + 256 + bcol] = f2bf(s);
    }
    BAR();

    f32x16 acc = {0,0,0,0,0,0,0,0,0,0,0,0,0,0,0,0};
    #pragma unroll
    for (int ks = 0; ks < 24; ++ks) {
      short8 a = *(const short8*)&hT[cur][arow * HS + ks * 16 + koff];
      acc = __builtin_amdgcn_mfma_f32_32x32x16_bf16(a, wb[ks], acc, 0, 0, 0);
    }

    if (hasnext) {
      #pragma unroll
      for (int rep = 0; rep < 2; ++rep) {
        int i = rep * 512 + t;
        int e_loc = i >> 4, r = i & 15;
        float d = dv[rep];
        float v = 0.63245553f * __sinf(d * (float)(r + 1) * 0.62831853f) / d;
        rbfb[cur ^ 1][e_loc * RS + r] = f2bf(v);
      }
      #pragma unroll
      for (int rep = 0; rep < 8; ++rep) {
        int idx   = rep * 512 + t;
        int which = idx >> 11, r2 = idx & 2047;
        int e_loc = r2 >> 5, q = r2 & 31;
        uint2 pv; pv.x = pk2(g4[rep].x, g4[rep].y); pv.y = pk2(g4[rep].z, g4[rep].w);
        *(uint2*)&hT[cur ^ 1][e_loc * HS + which * 128 + q * 4] = pv;
      }
    }

    #pragma unroll
    for (int i = 0; i < 16; ++i) {
      int row   = (i & 3) + 8 * (i >> 2) + 4 * hi;
      int e_loc = er * 32 + row;
      float x  = acc[i] + bl;
      float e1 = x / (1.f + __expf(-x));
      float e2 = sacc[i] * e1;
      long gi = (long)(e0 + e_loc) * HID + bcol;
      __builtin_nontemporal_store(e1, &out[gi]);
      __builtin_nontemporal_store(e2, &out[(long)E_EDGES * HID + gi]);
    }
    BAR();
    cur ^= 1;
  }
}

extern "C" void kernel_launch(void* const* d_in, const int* in_sizes, int n_in,
                              void* d_out, int out_size, void* d_ws, size_t ws_size,
                              hipStream_t stream) {
  const float* node_embs = (const float*)d_in[0];
  const int*   eidx      = (const int*)d_in[1];
  const float* ew        = (const float*)d_in[2];
  const float* Wrbf0     = (const float*)d_in[3];
  const float* brbf0     = (const float*)d_in[4];
  const float* Wlin      = (const float*)d_in[5];
  const float* blin      = (const float*)d_in[6];
  const float* Wrbf1     = (const float*)d_in[7];
  float* out = (float*)d_out;

  if (ws_size >= (size_t)WT_BYTES) {
    unsigned short* Wt = (unsigned short*)d_ws;
    wt_prep_kernel<<<(K3 * HID + 255) / 256, 256, 0, stream>>>(Wlin, Wt);
    edge_feat_kernel2<<<512, 512, 0, stream>>>(node_embs, eidx, ew, Wrbf0, brbf0,
                                               Wt, blin, Wrbf1, out);
  } else {
    edge_feat_kernel_fb<<<256, 512, 0, stream>>>(node_embs, eidx, ew, Wrbf0, brbf0,
                                                 Wlin, blin, Wrbf1, out);
  }
}

// Round 5
// 128.062 us; speedup vs baseline: 1.4104x; 1.4104x over previous
//
#include <hip/hip_runtime.h>

#define E_EDGES 320000
#define N_NODES 20000
#define HID 128
#define K3 384
#define NR 16
#define TILE_E 32
#define NTILES (E_EDGES / TILE_E)   // 10000
#define RS 24     // rbf row stride (bf16 elems)
#define NS 136    // prep LDS row stride
#define R0S 136   // rbf0 LDS row stride

// ---- workspace layout (bytes) ----
#define P_BYTES   (N_NODES * 256 * 4)          // Pcat f32 [node][256]
#define W3T_OFF   P_BYTES
#define W3T_BYTES (HID * HID * 2)              // W3^T bf16 [col][128]
#define W0T_OFF   (W3T_OFF + W3T_BYTES)
#define W0T_BYTES (HID * NR * 2)               // W0^T bf16 [col][16]
#define W1T_OFF   (W0T_OFF + W0T_BYTES)
#define WS_NEED   (W1T_OFF + W0T_BYTES)

typedef float f32x16 __attribute__((ext_vector_type(16)));
typedef short short8 __attribute__((ext_vector_type(8)));

__device__ __forceinline__ unsigned short f2bf(float x) {
  union { float f; unsigned u; } v; v.f = x;
  unsigned u = v.u + 0x7fffu + ((v.u >> 16) & 1u);   // RNE
  return (unsigned short)(u >> 16);
}
__device__ __forceinline__ unsigned pk2(float a, float b) {
  union { float f; unsigned u; } va, vb; va.f = a; vb.f = b;
  unsigned ua = va.u + 0x7fffu + ((va.u >> 16) & 1u);
  unsigned ub = vb.u + 0x7fffu + ((vb.u >> 16) & 1u);
  return (ua >> 16) | (ub & 0xffff0000u);
}

#define BAR() asm volatile("s_waitcnt lgkmcnt(0)\n\ts_barrier" ::: "memory")

// ---- prep A: small weight transposes into ws ----
__global__ __launch_bounds__(256)
void wsmall_prep(const float* __restrict__ Wlin, const float* __restrict__ Wrbf0,
                 const float* __restrict__ Wrbf1, unsigned short* __restrict__ W3t,
                 unsigned short* __restrict__ W0t, unsigned short* __restrict__ W1t)
{
  int i = blockIdx.x * 256 + threadIdx.x;
  if (i < 16384) {                       // W3t[col][k] = Wlin[256+k][col]
    int col = i >> 7, k = i & 127;
    W3t[col * 128 + k] = f2bf(Wlin[(256 + k) * HID + col]);
  } else if (i < 16384 + 2048) {         // W0t[col][r]
    int j = i - 16384, col = j >> 4, r = j & 15;
    W0t[col * 16 + r] = f2bf(Wrbf0[r * HID + col]);
  } else if (i < 16384 + 4096) {         // W1t[col][r]
    int j = i - 16384 - 2048, col = j >> 4, r = j & 15;
    W1t[col * 16 + r] = f2bf(Wrbf1[r * HID + col]);
  }
}

// ---- prep B: Pcat[n][c] = node_embs @ [W1 || W2]  (64-node tiles, MFMA) ----
__global__ __launch_bounds__(512, 2)
void p_prep_kernel(const float* __restrict__ ne, const float* __restrict__ Wlin,
                   float* __restrict__ P)
{
  __shared__ __align__(16) unsigned short WtL[256 * NS];  // Wcat^T [c][k]
  __shared__ __align__(16) unsigned short ndL[64 * NS];   // nodes  [r][k]

  const int t    = threadIdx.x;
  const int lane = t & 63;
  const int w    = t >> 6;
  const int er   = w >> 2, cc = w & 3;
  const int l31  = lane & 31, hi = lane >> 5;
  const int koff = hi * 8;
  const int n0   = blockIdx.x * 64;

  // stage Wcat^T: half 1 (c<128 from Wlin rows 0..127)
  #pragma unroll
  for (int rep = 0; rep < 8; ++rep) {
    int idx = rep * 512 + t;            // 0..4095 float4s
    int k = idx >> 5, c4 = idx & 31;
    float4 v = ((const float4*)Wlin)[idx];
    WtL[(4 * c4 + 0) * NS + k] = f2bf(v.x);
    WtL[(4 * c4 + 1) * NS + k] = f2bf(v.y);
    WtL[(4 * c4 + 2) * NS + k] = f2bf(v.z);
    WtL[(4 * c4 + 3) * NS + k] = f2bf(v.w);
  }
  // half 2 (c in [128,256) from Wlin rows 128..255)
  #pragma unroll
  for (int rep = 0; rep < 8; ++rep) {
    int idx = rep * 512 + t;
    int k = idx >> 5, c4 = idx & 31;
    float4 v = ((const float4*)Wlin)[4096 + idx];
    WtL[(128 + 4 * c4 + 0) * NS + k] = f2bf(v.x);
    WtL[(128 + 4 * c4 + 1) * NS + k] = f2bf(v.y);
    WtL[(128 + 4 * c4 + 2) * NS + k] = f2bf(v.z);
    WtL[(128 + 4 * c4 + 3) * NS + k] = f2bf(v.w);
  }
  // stage 64 node rows (clamped)
  #pragma unroll
  for (int rep = 0; rep < 4; ++rep) {
    int idx = rep * 512 + t;            // 0..2047 float4s
    int r = idx >> 5, q = idx & 31;
    int n = n0 + r; if (n > N_NODES - 1) n = N_NODES - 1;
    float4 v = ((const float4*)ne)[n * 32 + q];
    uint2 pv; pv.x = pk2(v.x, v.y); pv.y = pk2(v.z, v.w);
    *(uint2*)&ndL[r * NS + q * 4] = pv;
  }
  BAR();

  const int arow = er * 32 + l31;
  #pragma unroll
  for (int cg = 0; cg < 2; ++cg) {
    int bcol2 = cg * 128 + cc * 32 + l31;
    f32x16 acc = {0,0,0,0,0,0,0,0,0,0,0,0,0,0,0,0};
    #pragma unroll
    for (int ks = 0; ks < 8; ++ks) {
      short8 a = *(const short8*)&ndL[arow * NS + ks * 16 + koff];
      short8 b = *(const short8*)&WtL[bcol2 * NS + ks * 16 + koff];
      acc = __builtin_amdgcn_mfma_f32_32x32x16_bf16(a, b, acc, 0, 0, 0);
    }
    #pragma unroll
    for (int i = 0; i < 16; ++i) {
      int row = (i & 3) + 8 * (i >> 2) + 4 * hi;
      int n = n0 + er * 32 + row;
      if (n < N_NODES) P[n * 256 + bcol2] = acc[i];
    }
  }
}

// ---- main: per 32-edge tile, K=128 GEMM + P gathers in epilogue ----
__global__ __launch_bounds__(256, 4)
void edge_feat_main(const int* __restrict__ eidx,
                    const float* __restrict__ ew,
                    const float* __restrict__ brbf0,
                    const float* __restrict__ blin,
                    const float* __restrict__ P,
                    const unsigned short* __restrict__ W3t,
                    const unsigned short* __restrict__ W0t,
                    const unsigned short* __restrict__ W1t,
                    float* __restrict__ out)
{
  __shared__ __align__(16) unsigned short rbf0L[TILE_E * R0S]; // 8704 B
  __shared__ __align__(16) unsigned short rbfb[TILE_E * RS];   // 1536 B
  __shared__ int eixL[64];                                     // src[32], dst[32]

  const int t    = threadIdx.x;
  const int lane = t & 63;
  const int cc   = t >> 6;          // 4 waves = 4 col-tiles
  const int l31  = lane & 31;
  const int hi   = lane >> 5;
  const int koff = hi * 8;
  const int ocol = cc * 32 + l31;
  const int e0   = blockIdx.x * TILE_E;
  const float bl = blin[ocol];
  const float b0 = brbf0[ocol];

  // per-wave B fragments from prepped transposes (vector b128 loads)
  short8 w0f = *(const short8*)&W0t[ocol * 16 + koff];
  short8 w1f = *(const short8*)&W1t[ocol * 16 + koff];
  short8 w3f[8];
  #pragma unroll
  for (int ks = 0; ks < 8; ++ks)
    w3f[ks] = *(const short8*)&W3t[ocol * 128 + ks * 16 + koff];

  // ---- stage: rbf + edge indices ----
  #pragma unroll
  for (int rep = 0; rep < 2; ++rep) {
    int i = rep * 256 + t;            // 0..511 = 32 edges x 16 radial
    int e_loc = i >> 4, r = i & 15;
    float d = ew[e0 + e_loc];
    float v = 0.63245553f * __sinf(d * (float)(r + 1) * 0.62831853f) / d;
    rbfb[e_loc * RS + r] = f2bf(v);
  }
  if (t < 32)       eixL[t]      = eidx[e0 + t];
  else if (t < 64)  eixL[t]      = eidx[E_EDGES + e0 + (t - 32)];
  BAR();

  // ---- issue P gathers early (latency hides under MFMA phases) ----
  float p1[16], p2[16];
  #pragma unroll
  for (int i = 0; i < 16; ++i) {
    int row = (i & 3) + 8 * (i >> 2) + 4 * hi;
    int sn = eixL[row], dn = eixL[32 + row];
    p1[i] = P[sn * 256 + ocol];
    p2[i] = P[dn * 256 + 128 + ocol];
  }

  // ---- rbf0 = silu(rbf @ W0 + b0) -> LDS ----
  short8 ra = *(const short8*)&rbfb[l31 * RS + koff];
  f32x16 r0 = {0,0,0,0,0,0,0,0,0,0,0,0,0,0,0,0};
  r0 = __builtin_amdgcn_mfma_f32_32x32x16_bf16(ra, w0f, r0, 0, 0, 0);
  #pragma unroll
  for (int i = 0; i < 16; ++i) {
    int row = (i & 3) + 8 * (i >> 2) + 4 * hi;
    float x = r0[i] + b0;
    float s = x / (1.f + __expf(-x));
    rbf0L[row * R0S + ocol] = f2bf(s);
  }
  BAR();

  // ---- main MFMA: acc = rbf0 @ W3 (K=128) ----
  f32x16 acc = {0,0,0,0,0,0,0,0,0,0,0,0,0,0,0,0};
  #pragma unroll
  for (int ks = 0; ks < 8; ++ks) {
    short8 a = *(const short8*)&rbf0L[l31 * R0S + ks * 16 + koff];
    acc = __builtin_amdgcn_mfma_f32_32x32x16_bf16(a, w3f[ks], acc, 0, 0, 0);
  }
  // sacc = rbf @ W1 (ra still in regs)
  f32x16 sacc = {0,0,0,0,0,0,0,0,0,0,0,0,0,0,0,0};
  sacc = __builtin_amdgcn_mfma_f32_32x32x16_bf16(ra, w1f, sacc, 0, 0, 0);

  // ---- epilogue ----
  #pragma unroll
  for (int i = 0; i < 16; ++i) {
    int row = (i & 3) + 8 * (i >> 2) + 4 * hi;
    float x  = acc[i] + p1[i] + p2[i] + bl;
    float e1 = x / (1.f + __expf(-x));
    float e2 = sacc[i] * e1;
    long gi = (long)(e0 + row) * HID + ocol;
    __builtin_nontemporal_store(e1, &out[gi]);
    __builtin_nontemporal_store(e2, &out[(long)E_EDGES * HID + gi]);
  }
}

// =============== fallback (R3 kernel, proven 129.8 us) ===============
#define HS 392
__global__ __launch_bounds__(512, 2)
void edge_feat_kernel_fb(const float* __restrict__ node_embs,
                         const int* __restrict__ eidx,
                         const float* __restrict__ ew,
                         const float* __restrict__ Wrbf0,
                         const float* __restrict__ brbf0,
                         const float* __restrict__ Wlin,
                         const float* __restrict__ blin,
                         const float* __restrict__ Wrbf1,
                         float* __restrict__ out)
{
  __shared__ __align__(16) unsigned short hT[2][64 * HS];
  __shared__ __align__(16) unsigned short rbfb2[2][64 * RS];

  const int t = threadIdx.x, lane = t & 63, w = t >> 6;
  const int er = w >> 2, cc = w & 3;
  const int l31 = lane & 31, hi = lane >> 5, koff = hi * 8;
  const int arow = er * 32 + l31, bcol = cc * 32 + l31;
  const float bl = blin[bcol], b0 = brbf0[bcol];

  {
    unsigned short* WtL = &hT[0][0];
    for (int i = t; i < K3 * HID; i += 512) {
      int k = i >> 7, col = i & 127;
      WtL[col * HS + k] = f2bf(Wlin[i]);
    }
    BAR();
  }
  short8 wb[24];
  #pragma unroll
  for (int ks = 0; ks < 24; ++ks)
    wb[ks] = *(const short8*)&hT[0][bcol * HS + ks * 16 + koff];
  asm volatile("s_waitcnt lgkmcnt(0)" ::: "memory");
  __builtin_amdgcn_s_barrier();

  short8 w0f, w1f;
  #pragma unroll
  for (int j = 0; j < 8; ++j) {
    w0f[j] = (short)f2bf(Wrbf0[(koff + j) * HID + bcol]);
    w1f[j] = (short)f2bf(Wrbf1[(koff + j) * HID + bcol]);
  }

  int tile = blockIdx.x;
  {
    #pragma unroll
    for (int rep = 0; rep < 8; ++rep) {
      int idx = rep * 512 + t;
      int which = idx >> 11, r2 = idx & 2047;
      int e_loc = r2 >> 5, q = r2 & 31;
      int node = eidx[which * E_EDGES + tile * 64 + e_loc];
      const float4 v = ((const float4*)node_embs)[node * 32 + q];
      uint2 pv; pv.x = pk2(v.x, v.y); pv.y = pk2(v.z, v.w);
      *(uint2*)&hT[0][e_loc * HS + which * 128 + q * 4] = pv;
    }
    #pragma unroll
    for (int rep = 0; rep < 2; ++rep) {
      int i = rep * 512 + t;
      int e_loc = i >> 4, r = i & 15;
      float d = ew[tile * 64 + e_loc];
      float v = 0.63245553f * __sinf(d * (float)(r + 1) * 0.62831853f) / d;
      rbfb2[0][e_loc * RS + r] = f2bf(v);
    }
  }
  BAR();

  int cur = 0;
  for (; tile < E_EDGES / 64; tile += (int)gridDim.x) {
    const int nt = tile + (int)gridDim.x;
    const bool hasnext = (nt < E_EDGES / 64);
    const int e0 = tile * 64;

    float4 g4[8]; float dv[2];
    if (hasnext) {
      #pragma unroll
      for (int rep = 0; rep < 8; ++rep) {
        int idx = rep * 512 + t;
        int which = idx >> 11, r2 = idx & 2047;
        int e_loc = r2 >> 5, q = r2 & 31;
        int node = eidx[which * E_EDGES + nt * 64 + e_loc];
        g4[rep] = ((const float4*)node_embs)[node * 32 + q];
      }
      #pragma unroll
      for (int rep = 0; rep < 2; ++rep)
        dv[rep] = ew[nt * 64 + ((rep * 512 + t) >> 4)];
    }

    f32x16 r0 = {0,0,0,0,0,0,0,0,0,0,0,0,0,0,0,0};
    f32x16 sacc = {0,0,0,0,0,0,0,0,0,0,0,0,0,0,0,0};
    short8 ra = *(const short8*)&rbfb2[cur][arow * RS + koff];
    r0   = __builtin_amdgcn_mfma_f32_32x32x16_bf16(ra, w0f, r0, 0, 0, 0);
    sacc = __builtin_amdgcn_mfma_f32_32x32x16_bf16(ra, w1f, sacc, 0, 0, 0);
    #pragma unroll
    for (int i = 0; i < 16; ++i) {
      int row = (i & 3) + 8 * (i >> 2) + 4 * hi;
      float x = r0[i] + b0;
      float s = x / (1.f + __expf(-x));
      hT[cur][(er * 32 + row) * HS + 256 + bcol] = f2bf(s);
    }
    BAR();

    f32x16 acc = {0,0,0,0,0,0,0,0,0,0,0,0,0,0,0,0};
    #pragma unroll
    for (int ks = 0; ks < 24; ++ks) {
      short8 a = *(const short8*)&hT[cur][arow * HS + ks * 16 + koff];
      acc = __builtin_amdgcn_mfma_f32_32x32x16_bf16(a, wb[ks], acc, 0, 0, 0);
    }

    if (hasnext) {
      #pragma unroll
      for (int rep = 0; rep < 2; ++rep) {
        int i = rep * 512 + t;
        int e_loc = i >> 4, r = i & 15;
        float d = dv[rep];
        float v = 0.63245553f * __sinf(d * (float)(r + 1) * 0.62831853f) / d;
        rbfb2[cur ^ 1][e_loc * RS + r] = f2bf(v);
      }
      #pragma unroll
      for (int rep = 0; rep < 8; ++rep) {
        int idx = rep * 512 + t;
        int which = idx >> 11, r2 = idx & 2047;
        int e_loc = r2 >> 5, q = r2 & 31;
        uint2 pv; pv.x = pk2(g4[rep].x, g4[rep].y); pv.y = pk2(g4[rep].z, g4[rep].w);
        *(uint2*)&hT[cur ^ 1][e_loc * HS + which * 128 + q * 4] = pv;
      }
    }

    #pragma unroll
    for (int i = 0; i < 16; ++i) {
      int row = (i & 3) + 8 * (i >> 2) + 4 * hi;
      int e_loc = er * 32 + row;
      float x = acc[i] + bl;
      float e1 = x / (1.f + __expf(-x));
      float e2 = sacc[i] * e1;
      long gi = (long)(e0 + e_loc) * HID + bcol;
      __builtin_nontemporal_store(e1, &out[gi]);
      __builtin_nontemporal_store(e2, &out[(long)E_EDGES * HID + gi]);
    }
    BAR();
    cur ^= 1;
  }
}

extern "C" void kernel_launch(void* const* d_in, const int* in_sizes, int n_in,
                              void* d_out, int out_size, void* d_ws, size_t ws_size,
                              hipStream_t stream) {
  const float* node_embs = (const float*)d_in[0];
  const int*   eidx      = (const int*)d_in[1];
  const float* ew        = (const float*)d_in[2];
  const float* Wrbf0     = (const float*)d_in[3];
  const float* brbf0     = (const float*)d_in[4];
  const float* Wlin      = (const float*)d_in[5];
  const float* blin      = (const float*)d_in[6];
  const float* Wrbf1     = (const float*)d_in[7];
  float* out = (float*)d_out;

  if (ws_size >= (size_t)WS_NEED) {
    char* ws = (char*)d_ws;
    float* P            = (float*)ws;
    unsigned short* W3t = (unsigned short*)(ws + W3T_OFF);
    unsigned short* W0t = (unsigned short*)(ws + W0T_OFF);
    unsigned short* W1t = (unsigned short*)(ws + W1T_OFF);

    wsmall_prep<<<80, 256, 0, stream>>>(Wlin, Wrbf0, Wrbf1, W3t, W0t, W1t);
    p_prep_kernel<<<(N_NODES + 63) / 64, 512, 0, stream>>>(node_embs, Wlin, P);
    edge_feat_main<<<NTILES, 256, 0, stream>>>(eidx, ew, brbf0, blin, P,
                                               W3t, W0t, W1t, out);
  } else {
    edge_feat_kernel_fb<<<256, 512, 0, stream>>>(node_embs, eidx, ew, Wrbf0, brbf0,
                                                 Wlin, blin, Wrbf1, out);
  }
}